// Round 16
// baseline (270.684 us; speedup 1.0000x reference)
//
#include <hip/hip_runtime.h>
#include <math.h>

#define H    768
#define NT   24           // W K-steps of 32
#define NM   6            // A macro-tiles of 128 cols
#define DIM  128
#define LQ   32
#define LD   512
#define BM   64           // tokens per block
#define EPSF 1e-12f

typedef _Float16 f16x8 __attribute__((ext_vector_type(8)));
typedef float    f32x4 __attribute__((ext_vector_type(4)));

static __device__ __forceinline__ unsigned short h2u(_Float16 h) {
    return __builtin_bit_cast(unsigned short, h);
}

#define GLOAD_LDS16(g, l) __builtin_amdgcn_global_load_lds(                    \
    (const __attribute__((address_space(1))) unsigned int*)(const void*)(g),   \
    (__attribute__((address_space(3))) unsigned int*)(void*)(l), 16, 0, 0)

// ------- W -> single f16 (pre-swizzled, R10 layout) + WT fp32 (qproj) --------
__global__ __launch_bounds__(256) void wconv_kernel(
    const float* __restrict__ W, unsigned short* __restrict__ wsW,
    float* __restrict__ WT)
{
    const int ks  = blockIdx.x;
    const int tid = threadIdx.x;
    #pragma unroll 4
    for (int i = 0; i < 16; ++i) {
        const int idx = tid + i * 256;          // 0..4095
        const int row = idx >> 5, col = idx & 31;
        const float x = W[(size_t)row * H + ks * 32 + col];
        const int colS = (((col >> 3) ^ ((row >> 1) & 3)) << 3) | (col & 7);
        wsW[((size_t)ks * 128 + row) * 32 + colS] = h2u((_Float16)x);
        WT[((size_t)ks * 32 + col) * DIM + row] = x;
    }
}

// ------- query projection (coalesced via WT, 2-way h-split) + L2 norm -------
__global__ __launch_bounds__(256) void qproj_kernel(
    const float* __restrict__ qh, const float* __restrict__ WT,
    unsigned short* __restrict__ qn)
{
    const int blk = blockIdx.x;   // 4 tokens per block
    const int tid = threadIdx.x;
    const int td  = tid & 127;
    const int hp  = tid >> 7;
    __shared__ float rows[4][H];
    __shared__ float psum[2][4][128];
    __shared__ float red[128];

    const float4* src = (const float4*)(qh + (size_t)blk * 4 * H);
    float4*       dst = (float4*)&rows[0][0];
    for (int i = tid; i < 4 * H / 4; i += 256) dst[i] = src[i];
    __syncthreads();

    float acc[4] = {0.f, 0.f, 0.f, 0.f};
    const int h0 = hp * (H / 2);
    #pragma unroll 8
    for (int h = h0; h < h0 + H / 2; ++h) {
        const float wv = WT[(size_t)h * DIM + td];
        acc[0] += wv * rows[0][h];
        acc[1] += wv * rows[1][h];
        acc[2] += wv * rows[2][h];
        acc[3] += wv * rows[3][h];
    }
    #pragma unroll
    for (int j = 0; j < 4; ++j) psum[hp][j][td] = acc[j];
    __syncthreads();

    #pragma unroll
    for (int j = 0; j < 4; ++j) {
        const float val = psum[0][j][td] + psum[1][j][td];
        if (hp == 0) red[td] = val * val;
        __syncthreads();
        for (int s = 64; s > 0; s >>= 1) {
            if (tid < s) red[tid] += red[tid + s];
            __syncthreads();
        }
        const float inv = 1.0f / fmaxf(sqrtf(red[0]), EPSF);
        if (hp == 0) qn[((size_t)blk * 4 + j) * DIM + td] = h2u((_Float16)(val * inv));
        __syncthreads();
    }
}

// ---- doc: A direct-to-register (512-B bursts, 2-macro dbuf), W LDS dbuf -----
struct Smem {
    union {
        unsigned short Wt[2][128][32];   // 16 KB W double buffer
        unsigned short C[BM][DIM];       // 16 KB epilogue overlay
    } u;
    float         pnorm[BM];
    unsigned char mk[BM];
    float         pmax[LQ][4];
};

__global__ __launch_bounds__(256, 4) void docgemm_kernel(
    const float* __restrict__ dh, const unsigned short* __restrict__ wsW,
    const int* __restrict__ dmask, const unsigned short* __restrict__ qn,
    float* __restrict__ part, const int* __restrict__ ppq_p)
{
    __shared__ Smem sm;
    const int blk = blockIdx.x;      // 2048 blocks
    const int b   = blk >> 3;        // doc
    const int c   = blk & 7;         // 64-token chunk
    const int tid = threadIdx.x;
    const int w   = tid >> 6;        // wave 0..3 (16 tokens each, all dims)
    const int l   = tid & 63;
    const int g   = l >> 4;
    const int r15 = l & 15;
    const int ppq = ppq_p[0];

    // per-lane A base in fragment layout: token row = l&15, k-sub = g*8
    const float* Aptr =
        dh + ((size_t)b * LD + c * BM + w * 16 + r15) * H + g * 8;

    f32x4 acc[8];
    #pragma unroll
    for (int n = 0; n < 8; ++n) acc[n] = (f32x4){0.f, 0.f, 0.f, 0.f};

    float4 rawA[8], rawB[8];   // 2-macro A buffer (static names)

#define LOADA(RAW, M)                                                          \
    _Pragma("unroll")                                                          \
    for (int kk = 0; kk < 4; ++kk) {                                           \
        RAW[kk * 2]     = *(const float4*)(Aptr + (M) * 128 + kk * 32);        \
        RAW[kk * 2 + 1] = *(const float4*)(Aptr + (M) * 128 + kk * 32 + 4);    \
    }

    // ---- prologue: W(0) (oldest), A(macro0), mask; drain all; barrier ----
    {
        const char* wt   = (const char*)wsW;
        char*       wdst = (char*)&sm.u.Wt[0][0][0];
        GLOAD_LDS16(wt + tid * 16,        wdst + w * 1024);
        GLOAD_LDS16(wt + 4096 + tid * 16, wdst + 4096 + w * 1024);
        __builtin_amdgcn_sched_barrier(0);
        LOADA(rawA, 0)
        if (tid < BM) sm.mk[tid] = (unsigned char)(dmask[(size_t)b * LD + c * BM + tid] != 0);
        asm volatile("s_waitcnt vmcnt(0) lgkmcnt(0)" ::: "memory");
        __builtin_amdgcn_sched_barrier(0);
        __builtin_amdgcn_s_barrier();
        __builtin_amdgcn_sched_barrier(0);
    }

    // ---- main loop, fully unrolled: 24 W-steps; A issued once per 4 steps ----
    #pragma unroll
    for (int t = 0; t < NT; ++t) {
        const int M   = t >> 2;      // current A macro (raw set M&1)
        const int kk  = t & 3;
        const int cur = t & 1, nxt = cur ^ 1;

        if (t + 1 < NT) {  // W(t+1) — issued FIRST (oldest)
            const char* wt   = (const char*)wsW + (size_t)(t + 1) * 8192;
            char*       wdst = (char*)&sm.u.Wt[nxt][0][0];
            GLOAD_LDS16(wt + tid * 16,        wdst + w * 1024);
            GLOAD_LDS16(wt + 4096 + tid * 16, wdst + 4096 + w * 1024);
        }
        if (kk == 0 && M + 1 < NM) {  // A(M+1) — youngest, stays in flight
            if ((M + 1) & 1) { LOADA(rawB, M + 1) }
            else             { LOADA(rawA, M + 1) }
        }
        __builtin_amdgcn_sched_barrier(0);

        // convert frag kk from macro M (drained >= 1 step ago: never stalls)
        f16x8 af;
        if (M & 1) {
            af[0] = (_Float16)rawB[kk*2].x;   af[1] = (_Float16)rawB[kk*2].y;
            af[2] = (_Float16)rawB[kk*2].z;   af[3] = (_Float16)rawB[kk*2].w;
            af[4] = (_Float16)rawB[kk*2+1].x; af[5] = (_Float16)rawB[kk*2+1].y;
            af[6] = (_Float16)rawB[kk*2+1].z; af[7] = (_Float16)rawB[kk*2+1].w;
        } else {
            af[0] = (_Float16)rawA[kk*2].x;   af[1] = (_Float16)rawA[kk*2].y;
            af[2] = (_Float16)rawA[kk*2].z;   af[3] = (_Float16)rawA[kk*2].w;
            af[4] = (_Float16)rawA[kk*2+1].x; af[5] = (_Float16)rawA[kk*2+1].y;
            af[6] = (_Float16)rawA[kk*2+1].z; af[7] = (_Float16)rawA[kk*2+1].w;
        }

        __builtin_amdgcn_s_setprio(1);
        #pragma unroll
        for (int n = 0; n < 8; ++n) {
            const int row = n * 16 + r15;
            const int sl  = (g ^ ((row >> 1) & 3)) * 8;
            f16x8 bh = *(const f16x8*)&sm.u.Wt[cur][row][sl];
            acc[n] = __builtin_amdgcn_mfma_f32_16x16x32_f16(af, bh, acc[n], 0, 0, 0);
        }
        __builtin_amdgcn_s_setprio(0);

        if (kk == 0 && M + 1 < NM) {
            asm volatile("s_waitcnt vmcnt(8) lgkmcnt(0)" ::: "memory");
        } else {
            asm volatile("s_waitcnt vmcnt(0) lgkmcnt(0)" ::: "memory");
        }
        __builtin_amdgcn_sched_barrier(0);
        __builtin_amdgcn_s_barrier();
        __builtin_amdgcn_sched_barrier(0);
    }

    // ---- epilogue 1: C -> LDS f16 (swizzled, overlays W) + per-token norms --
    __builtin_amdgcn_s_barrier();   // all waves done with W LDS
    #pragma unroll
    for (int n = 0; n < 8; ++n) {
        const int dim = n * 16 + r15;
        #pragma unroll
        for (int r = 0; r < 4; ++r) {
            const int tok  = w * 16 + g * 4 + r;
            const int slot = (dim >> 3) ^ (tok & 7);
            sm.u.C[tok][slot * 8 + (dim & 7)] = h2u((_Float16)acc[n][r]);
        }
    }
    #pragma unroll
    for (int r = 0; r < 4; ++r) {
        float s = 0.f;
        #pragma unroll
        for (int n = 0; n < 8; ++n) s += acc[n][r] * acc[n][r];
        s += __shfl_xor(s, 1); s += __shfl_xor(s, 2);
        s += __shfl_xor(s, 4); s += __shfl_xor(s, 8);
        if (r15 == 0) sm.pnorm[w * 16 + g * 4 + r] = s;
    }
    __syncthreads();

    // ---- epilogue 2: sim [32 q] x [16 tokens per wave], K=128 ----
    const unsigned short* qb = qn + (size_t)(b / ppq) * LQ * DIM;
    const int tok = w * 16 + r15;
    const float inv = 1.0f / fmaxf(sqrtf(sm.pnorm[tok]), EPSF);
    const int msk = sm.mk[tok];

    f32x4 sacc[2];
    sacc[0] = (f32x4){0.f, 0.f, 0.f, 0.f};
    sacc[1] = (f32x4){0.f, 0.f, 0.f, 0.f};
    #pragma unroll
    for (int ks = 0; ks < 4; ++ks) {
        const int slot = (ks * 4 + g) ^ (tok & 7);
        f16x8 cb = *(const f16x8*)&sm.u.C[tok][slot * 8];
        #pragma unroll
        for (int m = 0; m < 2; ++m) {
            f16x8 qa = *(const f16x8*)(qb + (size_t)(m * 16 + r15) * DIM + ks * 32 + g * 8);
            sacc[m] = __builtin_amdgcn_mfma_f32_16x16x32_f16(qa, cb, sacc[m], 0, 0, 0);
        }
    }

    #pragma unroll
    for (int m = 0; m < 2; ++m) {
        #pragma unroll
        for (int r = 0; r < 4; ++r) {
            float v = msk ? sacc[m][r] * inv : -INFINITY;
            v = fmaxf(v, __shfl_xor(v, 1));
            v = fmaxf(v, __shfl_xor(v, 2));
            v = fmaxf(v, __shfl_xor(v, 4));
            v = fmaxf(v, __shfl_xor(v, 8));
            if (r15 == 0) sm.pmax[m * 16 + g * 4 + r][w] = v;
        }
    }
    __syncthreads();
    if (tid < LQ) {
        float mv = fmaxf(fmaxf(sm.pmax[tid][0], sm.pmax[tid][1]),
                         fmaxf(sm.pmax[tid][2], sm.pmax[tid][3]));
        part[(size_t)blk * 32 + tid] = mv;
    }
#undef LOADA
}

// ---------------- final: max over 8 chunks, sum over queries ----------------
__global__ __launch_bounds__(64) void final_kernel(
    const float* __restrict__ part, float* __restrict__ out)
{
    const int b = blockIdx.x;
    const int q = threadIdx.x & 31;
    const int h = threadIdx.x >> 5;
    const float* p = part + (size_t)b * 256;
    float m = -INFINITY;
    #pragma unroll
    for (int j = 0; j < 4; ++j)
        m = fmaxf(m, p[(h * 4 + j) * 32 + q]);
    m = fmaxf(m, __shfl_xor(m, 32));
    if (threadIdx.x < 32) {
        #pragma unroll
        for (int off = 1; off < 32; off <<= 1) m += __shfl_xor(m, off);
        if (threadIdx.x == 0) out[b] = m;
    }
}

extern "C" void kernel_launch(void* const* d_in, const int* in_sizes, int n_in,
                              void* d_out, int out_size, void* d_ws, size_t ws_size,
                              hipStream_t stream) {
    const float* qh    = (const float*)d_in[0];
    const float* dh    = (const float*)d_in[1];
    const float* W     = (const float*)d_in[2];
    const int*   dmask = (const int*)d_in[3];
    const int*   ppq   = (const int*)d_in[4];
    float*       out   = (float*)d_out;

    unsigned short* wsW  = (unsigned short*)d_ws;                      // 192 KB
    float*          WT   = (float*)((char*)d_ws + 196608);             // 384 KB
    unsigned short* qn   = (unsigned short*)((char*)d_ws + 589824);    // 256 KB
    float*          part = (float*)((char*)d_ws + 851968);             // 256 KB

    const int nq = in_sizes[0] / H;      // 1024 query tokens
    const int Bd = out_size;             // 256 docs

    wconv_kernel<<<NT, 256, 0, stream>>>(W, wsW, WT);
    qproj_kernel<<<nq / 4, 256, 0, stream>>>(qh, WT, qn);
    docgemm_kernel<<<Bd * 8, 256, 0, stream>>>(dh, wsW, dmask, qn, part, ppq);
    final_kernel<<<Bd, 64, 0, stream>>>(part, out);
}

// Round 17
// 176.771 us; speedup vs baseline: 1.5313x; 1.5313x over previous
//
#include <hip/hip_runtime.h>
#include <math.h>

#define H    768
#define NT   24           // K-tiles of 32
#define DIM  128
#define LQ   32
#define LD   512
#define BM   32           // tokens per block (full-H bulk-staged)
#define EPSF 1e-12f

typedef _Float16 f16x8 __attribute__((ext_vector_type(8)));
typedef _Float16 f16x4 __attribute__((ext_vector_type(4)));
typedef float    f32x4 __attribute__((ext_vector_type(4)));

static __device__ __forceinline__ unsigned short h2u(_Float16 h) {
    return __builtin_bit_cast(unsigned short, h);
}

// ------- W -> single f16 [ks][dim][32] UNSWIZZLED (register loads) + WT -----
__global__ __launch_bounds__(256) void wconv_kernel(
    const float* __restrict__ W, unsigned short* __restrict__ wsW,
    float* __restrict__ WT)
{
    const int ks  = blockIdx.x;
    const int tid = threadIdx.x;
    #pragma unroll 4
    for (int i = 0; i < 16; ++i) {
        const int idx = tid + i * 256;          // 0..4095
        const int row = idx >> 5, col = idx & 31;
        const float x = W[(size_t)row * H + ks * 32 + col];
        wsW[((size_t)ks * 128 + row) * 32 + col] = h2u((_Float16)x);
        WT[((size_t)ks * 32 + col) * DIM + row] = x;
    }
}

// ------- query projection (coalesced via WT) + L2 norm -> f16 (R10 ver) -----
__global__ __launch_bounds__(128) void qproj_kernel(
    const float* __restrict__ qh, const float* __restrict__ WT,
    unsigned short* __restrict__ qn)
{
    const int blk = blockIdx.x;   // 4 tokens per block
    const int tid = threadIdx.x;  // = output dim
    __shared__ float rows[4][H];
    __shared__ float red[128];

    const float4* src = (const float4*)(qh + (size_t)blk * 4 * H);
    float4*       dst = (float4*)&rows[0][0];
    for (int i = tid; i < 4 * H / 4; i += 128) dst[i] = src[i];
    __syncthreads();

    float acc[4] = {0.f, 0.f, 0.f, 0.f};
    #pragma unroll 8
    for (int h = 0; h < H; ++h) {
        const float wv = WT[(size_t)h * DIM + tid];   // coalesced across lanes
        acc[0] += wv * rows[0][h];
        acc[1] += wv * rows[1][h];
        acc[2] += wv * rows[2][h];
        acc[3] += wv * rows[3][h];
    }
    #pragma unroll
    for (int j = 0; j < 4; ++j) {
        red[tid] = acc[j] * acc[j];
        __syncthreads();
        for (int s = 64; s > 0; s >>= 1) {
            if (tid < s) red[tid] += red[tid + s];
            __syncthreads();
        }
        const float inv = 1.0f / fmaxf(sqrtf(red[0]), EPSF);
        qn[((size_t)blk * 4 + j) * DIM + tid] = h2u((_Float16)(acc[j] * inv));
        __syncthreads();
    }
}

// -- doc: contiguous A bulk-stage; barrier-free K-loop; W 3-set reg prefetch --
struct Smem {
    union {
        unsigned short A[BM][H];      // 48 KB (K-loop, granule-XOR-swizzled)
        unsigned short C[BM][DIM];    // 8 KB  (epilogue overlay)
    } u;
    float          pnorm[2][BM];
    unsigned char  mk[BM];
    float          pmax[LQ][2];
};

__global__ __launch_bounds__(256, 3) void docgemm_kernel(
    const float* __restrict__ dh, const unsigned short* __restrict__ wsW,
    const int* __restrict__ dmask, const unsigned short* __restrict__ qn,
    float* __restrict__ part, const int* __restrict__ ppq_p)
{
    __shared__ Smem sm;
    const int blk = blockIdx.x;          // 4096 blocks
    const int b   = blk >> 4;            // doc
    const int c   = blk & 15;            // 32-token chunk
    const int tid = threadIdx.x;
    const int w   = tid >> 6;            // wave 0..3
    const int m   = w & 1;               // token tile (16 tokens)
    const int nq  = w >> 1;              // dim half (64 dims)
    const int l   = tid & 63;
    const int g   = l >> 4;
    const int r15 = l & 15;
    const int ppq = ppq_p[0];

    // ---- stage: 32 rows x 768 fp32 = 96 KB contiguous -> f16 LDS (swizzled)
    {
        const float4* gsrc = (const float4*)(dh + (size_t)blk * BM * H);
        char* abase = (char*)&sm.u.A[0][0];
        #pragma unroll 8
        for (int j = 0; j < 24; ++j) {
            const int idx = tid + j * 256;      // float4 index 0..6143
            const float4 v = gsrc[idx];
            const int row = idx / 192;          // 192 float4 per row
            const int c4  = idx % 192;
            const int gr  = c4 >> 1;            // 16-B granule 0..95
            const int sub = (c4 & 1) * 8;       // byte offset in granule
            f16x4 h;
            h[0] = (_Float16)v.x; h[1] = (_Float16)v.y;
            h[2] = (_Float16)v.z; h[3] = (_Float16)v.w;
            *(f16x4*)(abase + (size_t)row * 1536 + ((gr ^ (row & 7)) << 4) + sub) = h;
        }
    }
    if (tid < BM) sm.mk[tid] = (unsigned char)(dmask[(size_t)b * LD + c * BM + tid] != 0);
    __syncthreads();

    // ---- K-loop: A from LDS, W via 3-set rotating register prefetch, no bars
    f32x4 acc[4];
    #pragma unroll
    for (int n = 0; n < 4; ++n) acc[n] = (f32x4){0.f, 0.f, 0.f, 0.f};

    const char* arow = (const char*)&sm.u.A[0][0] + (size_t)(m * 16 + r15) * 1536;
    const int   arsw = (m * 16 + r15) & 7;
    const unsigned short* wlane = wsW + (size_t)(nq * 64 + r15) * 32 + g * 8;

#define LW(S, T)                                                               \
    { _Pragma("unroll")                                                        \
      for (int n = 0; n < 4; ++n)                                              \
          S[n] = *(const f16x8*)(wlane + (size_t)(T) * 4096 + n * 512); }

#define STEP(T, SS, SN, TN)                                                    \
    {                                                                          \
        if ((TN) < NT) LW(SN, TN)                                              \
        const f16x8 af = *(const f16x8*)(arow + ((((T) * 4 + g) ^ arsw) << 4));\
        __builtin_amdgcn_s_setprio(1);                                         \
        _Pragma("unroll")                                                      \
        for (int n = 0; n < 4; ++n)                                            \
            acc[n] = __builtin_amdgcn_mfma_f32_16x16x32_f16(af, SS[n], acc[n], 0, 0, 0); \
        __builtin_amdgcn_s_setprio(0);                                         \
    }

    f16x8 S0[4], S1[4], S2[4];
    LW(S0, 0)
    LW(S1, 1)
    for (int t = 0; t < NT; t += 3) {
        STEP(t,     S0, S2, t + 2)
        STEP(t + 1, S1, S0, t + 3)
        STEP(t + 2, S2, S1, t + 4)
    }
#undef STEP
#undef LW

    __syncthreads();   // all waves done reading A before C overlays it

    // ---- epilogue 1: C -> LDS f16 (granule-swizzled) + per-token norms -----
    #pragma unroll
    for (int n = 0; n < 4; ++n) {
        const int dim = nq * 64 + n * 16 + r15;
        #pragma unroll
        for (int r = 0; r < 4; ++r) {
            const int tok  = m * 16 + g * 4 + r;
            const int slot = (dim >> 3) ^ (tok & 7);
            sm.u.C[tok][slot * 8 + (dim & 7)] = h2u((_Float16)acc[n][r]);
        }
    }
    #pragma unroll
    for (int r = 0; r < 4; ++r) {
        float s = 0.f;
        #pragma unroll
        for (int n = 0; n < 4; ++n) s += acc[n][r] * acc[n][r];
        s += __shfl_xor(s, 1); s += __shfl_xor(s, 2);
        s += __shfl_xor(s, 4); s += __shfl_xor(s, 8);
        if (r15 == 0) sm.pnorm[nq][m * 16 + g * 4 + r] = s;
    }
    __syncthreads();

    // ---- epilogue 2: sim [2 q-tiles x 2 tok-tiles over 4 waves], K=128 -----
    const unsigned short* qb = qn + (size_t)(b / ppq) * LQ * DIM;
    const int qm  = w >> 1;              // query tile
    const int tn  = w & 1;               // token tile
    const int tok = tn * 16 + r15;
    const float inv = 1.0f / fmaxf(sqrtf(sm.pnorm[0][tok] + sm.pnorm[1][tok]), EPSF);
    const int msk = sm.mk[tok];

    f32x4 sacc = (f32x4){0.f, 0.f, 0.f, 0.f};
    #pragma unroll
    for (int ks = 0; ks < 4; ++ks) {
        f16x8 qa = *(const f16x8*)(qb + (size_t)(qm * 16 + r15) * DIM + ks * 32 + g * 8);
        const int slot = (ks * 4 + g) ^ (tok & 7);
        f16x8 cb = *(const f16x8*)&sm.u.C[tok][slot * 8];
        sacc = __builtin_amdgcn_mfma_f32_16x16x32_f16(qa, cb, sacc, 0, 0, 0);
    }

    #pragma unroll
    for (int r = 0; r < 4; ++r) {
        float v = msk ? sacc[r] * inv : -INFINITY;
        v = fmaxf(v, __shfl_xor(v, 1));
        v = fmaxf(v, __shfl_xor(v, 2));
        v = fmaxf(v, __shfl_xor(v, 4));
        v = fmaxf(v, __shfl_xor(v, 8));
        if (r15 == 0) sm.pmax[qm * 16 + g * 4 + r][tn] = v;
    }
    __syncthreads();
    if (tid < LQ)
        part[(size_t)blk * LQ + tid] = fmaxf(sm.pmax[tid][0], sm.pmax[tid][1]);
}

// ---------------- final: max over 16 chunks, sum over 32 queries -------------
__global__ __launch_bounds__(64) void final_kernel(
    const float* __restrict__ part, float* __restrict__ out)
{
    const int b = blockIdx.x;
    const int q = threadIdx.x & 31;
    const int h = threadIdx.x >> 5;          // chunk half
    const float* p = part + (size_t)b * 16 * LQ;
    float m = -INFINITY;
    #pragma unroll
    for (int cchunk = 0; cchunk < 8; ++cchunk)
        m = fmaxf(m, p[(h * 8 + cchunk) * LQ + q]);
    m = fmaxf(m, __shfl_xor(m, 32));
    if (threadIdx.x < 32) {
        #pragma unroll
        for (int off = 1; off < 32; off <<= 1) m += __shfl_xor(m, off);
        if (threadIdx.x == 0) out[b] = m;
    }
}

extern "C" void kernel_launch(void* const* d_in, const int* in_sizes, int n_in,
                              void* d_out, int out_size, void* d_ws, size_t ws_size,
                              hipStream_t stream) {
    const float* qh    = (const float*)d_in[0];
    const float* dh    = (const float*)d_in[1];
    const float* W     = (const float*)d_in[2];
    const int*   dmask = (const int*)d_in[3];
    const int*   ppq   = (const int*)d_in[4];
    float*       out   = (float*)d_out;

    unsigned short* wsW  = (unsigned short*)d_ws;                      // 192 KB
    float*          WT   = (float*)((char*)d_ws + 196608);             // 384 KB
    unsigned short* qn   = (unsigned short*)((char*)d_ws + 589824);    // 256 KB
    float*          part = (float*)((char*)d_ws + 851968);             // 512 KB

    const int nq = in_sizes[0] / H;      // 1024 query tokens
    const int Bd = out_size;             // 256 docs

    wconv_kernel<<<NT, 256, 0, stream>>>(W, wsW, WT);
    qproj_kernel<<<nq / 4, 128, 0, stream>>>(qh, WT, qn);
    docgemm_kernel<<<Bd * 16, 256, 0, stream>>>(dh, wsW, dmask, qn, part, ppq);
    final_kernel<<<Bd, 64, 0, stream>>>(part, out);
}